// Round 1
// baseline (187.580 us; speedup 1.0000x reference)
//
#include <hip/hip_runtime.h>
#include <math.h>

#define EPSN 1e-12f

static constexpr int NB = 64;
static constexpr int NT = 4096;
static constexpr int ND = 1024;

// ---------------------------------------------------------------------------
// Kernel 1: per-batch lang norm.  64 blocks x 256 threads, D=1024 floats each.
// ---------------------------------------------------------------------------
__global__ void lang_norm_kernel(const float* __restrict__ lang,
                                 float* __restrict__ lnorm) {
    const int b = blockIdx.x;
    const int tid = threadIdx.x;             // 256 threads, one float4 each
    const float4* l4 = reinterpret_cast<const float4*>(lang + (size_t)b * ND);
    float4 v = l4[tid];
    float s = v.x * v.x + v.y * v.y + v.z * v.z + v.w * v.w;

    __shared__ float red[256];
    red[tid] = s;
    __syncthreads();
    for (int off = 128; off > 0; off >>= 1) {
        if (tid < off) red[tid] += red[tid + off];
        __syncthreads();
    }
    if (tid == 0) lnorm[b] = fmaxf(sqrtf(red[0]), EPSN);
}

// ---------------------------------------------------------------------------
// Kernel 2: one wave (64 lanes) per (b,t) row.
// Each lane: 4 x float4 of video (coalesced) + matching lang float4s.
// Butterfly shfl reduce dot & sumsq, lane 0 writes sim.
// ---------------------------------------------------------------------------
__global__ void sim_kernel(const float* __restrict__ video,
                           const float* __restrict__ lang,
                           const float* __restrict__ lnorm,
                           float* __restrict__ sim) {
    const int row  = (int)((blockIdx.x * (size_t)blockDim.x + threadIdx.x) >> 6);
    const int lane = threadIdx.x & 63;
    if (row >= NB * NT) return;
    const int b = row >> 12;                 // row / 4096

    const float4* v4 = reinterpret_cast<const float4*>(video + (size_t)row * ND);
    const float4* l4 = reinterpret_cast<const float4*>(lang + (size_t)b * ND);

    float d = 0.f, s = 0.f;
#pragma unroll
    for (int k = 0; k < 4; ++k) {
        float4 v = v4[lane + 64 * k];
        float4 l = l4[lane + 64 * k];
        d += v.x * l.x + v.y * l.y + v.z * l.z + v.w * l.w;
        s += v.x * v.x + v.y * v.y + v.z * v.z + v.w * v.w;
    }
#pragma unroll
    for (int off = 32; off > 0; off >>= 1) {
        d += __shfl_xor(d, off);
        s += __shfl_xor(s, off);
    }
    if (lane == 0) {
        float vn = fmaxf(sqrtf(s), EPSN);
        sim[row] = d / (vn * lnorm[b]);
    }
}

// ---------------------------------------------------------------------------
// Kernel 3: per-batch segment extraction.  64 blocks x 256 threads.
// Replicates jnp.argmax first-occurrence tie-break, then the start/end logic.
// ---------------------------------------------------------------------------
__global__ void segment_kernel(const float* __restrict__ sim,
                               const float* __restrict__ delta_p,
                               int* __restrict__ out) {
    const int b = blockIdx.x;
    const int tid = threadIdx.x;             // 256
    const float* s = sim + (size_t)b * NT;
    const float delta = *delta_p;

    // Phase 1: argmax with first-occurrence tie-break.
    float bestv = -INFINITY;
    int besti = NT;                          // larger than any valid index
    for (int t = tid; t < NT; t += 256) {
        float v = s[t];
        if (v > bestv || (v == bestv && t < besti)) { bestv = v; besti = t; }
    }
    __shared__ float sv[256];
    __shared__ int si[256];
    sv[tid] = bestv; si[tid] = besti;
    __syncthreads();
    for (int off = 128; off > 0; off >>= 1) {
        if (tid < off) {
            float ov = sv[tid + off];
            int   oi = si[tid + off];
            if (ov > sv[tid] || (ov == sv[tid] && oi < si[tid])) {
                sv[tid] = ov; si[tid] = oi;
            }
        }
        __syncthreads();
    }
    const int peak = si[0];
    const float peak_val = sv[0];
    __syncthreads();

    // Phase 2: last bad index < peak (max), first bad index > peak (min).
    int lb = -1, fb = NT;
    for (int t = tid; t < NT; t += 256) {
        float v = s[t];
        bool bad = fabsf(v - peak_val) > delta;
        if (bad) {
            if (t < peak && t > lb) lb = t;
            if (t > peak && t < fb) fb = t;
        }
    }
    __shared__ int slb[256];
    __shared__ int sfb[256];
    slb[tid] = lb; sfb[tid] = fb;
    __syncthreads();
    for (int off = 128; off > 0; off >>= 1) {
        if (tid < off) {
            slb[tid] = max(slb[tid], slb[tid + off]);
            sfb[tid] = min(sfb[tid], sfb[tid + off]);
        }
        __syncthreads();
    }

    if (tid == 0) {
        const int last_bad  = slb[0];
        const int first_bad = sfb[0];
        const int start0 = last_bad + 1;
        const int start  = (start0 == peak) ? start0 : start0 + 1;
        const int end0   = first_bad - 1;
        const int end    = (end0 == peak) ? end0 : end0 - 1;
        out[b]      = start;   // output 0: start, int32
        out[NB + b] = end;     // output 1: end,   int32
    }
}

// ---------------------------------------------------------------------------
extern "C" void kernel_launch(void* const* d_in, const int* in_sizes, int n_in,
                              void* d_out, int out_size, void* d_ws, size_t ws_size,
                              hipStream_t stream) {
    const float* video   = (const float*)d_in[0];   // (64, 4096, 1024) f32
    const float* lang    = (const float*)d_in[1];   // (64, 1, 1024)    f32
    const float* delta_p = (const float*)d_in[2];   // scalar f32
    int* out = (int*)d_out;                         // 64 starts, then 64 ends

    float* ws    = (float*)d_ws;
    float* lnorm = ws;                              // 64 floats
    float* sim   = ws + 256;                        // 262144 floats (aligned pad)

    lang_norm_kernel<<<NB, 256, 0, stream>>>(lang, lnorm);

    const int rows = NB * NT;                       // 262144 rows, 4 rows/block
    sim_kernel<<<rows / 4, 256, 0, stream>>>(video, lang, lnorm, sim);

    segment_kernel<<<NB, 256, 0, stream>>>(sim, delta_p, out);
}

// Round 2
// 162.249 us; speedup vs baseline: 1.1561x; 1.1561x over previous
//
#include <hip/hip_runtime.h>
#include <math.h>

#define EPSN 1e-12f

static constexpr int NB = 64;
static constexpr int NT = 4096;
static constexpr int ND = 1024;

typedef float floatx4 __attribute__((ext_vector_type(4)));

// ---------------------------------------------------------------------------
// Kernel 1 (fused): one wave (64 lanes) per (b,t) row.
// Each lane: 4 x float4 of video (non-temporal, coalesced) + matching lang
// float4s (cached, L1-resident per batch). Butterfly shfl reduce for
// dot(v,l), sumsq(v), sumsq(l); lane 0 writes sim = d/(max(|v|,eps)*max(|l|,eps)).
// ---------------------------------------------------------------------------
__global__ void sim_kernel(const float* __restrict__ video,
                           const float* __restrict__ lang,
                           float* __restrict__ sim) {
    const int row  = (int)((blockIdx.x * (size_t)blockDim.x + threadIdx.x) >> 6);
    const int lane = threadIdx.x & 63;
    if (row >= NB * NT) return;
    const int b = row >> 12;                 // row / 4096

    const floatx4* v4 = reinterpret_cast<const floatx4*>(video + (size_t)row * ND);
    const floatx4* l4 = reinterpret_cast<const floatx4*>(lang + (size_t)b * ND);

    float d = 0.f, s = 0.f, q = 0.f;
#pragma unroll
    for (int k = 0; k < 4; ++k) {
        floatx4 v = __builtin_nontemporal_load(&v4[lane + 64 * k]);
        floatx4 l = l4[lane + 64 * k];
        d += v.x * l.x + v.y * l.y + v.z * l.z + v.w * l.w;
        s += v.x * v.x + v.y * v.y + v.z * v.z + v.w * v.w;
        q += l.x * l.x + l.y * l.y + l.z * l.z + l.w * l.w;
    }
#pragma unroll
    for (int off = 32; off > 0; off >>= 1) {
        d += __shfl_xor(d, off);
        s += __shfl_xor(s, off);
        q += __shfl_xor(q, off);
    }
    if (lane == 0) {
        float vn = fmaxf(sqrtf(s), EPSN);
        float ln = fmaxf(sqrtf(q), EPSN);
        sim[row] = d / (vn * ln);
    }
}

// ---------------------------------------------------------------------------
// Kernel 2: per-batch segment extraction.  64 blocks x 1024 threads.
// Stage the 4096-float sim row in LDS, then argmax (first-occurrence
// tie-break, matching jnp.argmax) and the last-bad/first-bad scans.
// ---------------------------------------------------------------------------
__global__ void __launch_bounds__(1024)
segment_kernel(const float* __restrict__ sim,
               const float* __restrict__ delta_p,
               int* __restrict__ out) {
    const int b = blockIdx.x;
    const int tid = threadIdx.x;             // 1024
    const float* s = sim + (size_t)b * NT;
    const float delta = *delta_p;

    __shared__ float srow[NT];               // 16 KB
#pragma unroll
    for (int k = 0; k < NT / 1024; ++k) srow[tid + 1024 * k] = s[tid + 1024 * k];
    __syncthreads();

    // Phase 1: argmax with first-occurrence tie-break.
    float bestv = -INFINITY;
    int besti = NT;
#pragma unroll
    for (int k = 0; k < NT / 1024; ++k) {
        int t = tid + 1024 * k;
        float v = srow[t];
        if (v > bestv || (v == bestv && t < besti)) { bestv = v; besti = t; }
    }
    __shared__ float sv[1024];
    __shared__ int   si[1024];
    sv[tid] = bestv; si[tid] = besti;
    __syncthreads();
    for (int off = 512; off > 0; off >>= 1) {
        if (tid < off) {
            float ov = sv[tid + off];
            int   oi = si[tid + off];
            if (ov > sv[tid] || (ov == sv[tid] && oi < si[tid])) {
                sv[tid] = ov; si[tid] = oi;
            }
        }
        __syncthreads();
    }
    const int peak = si[0];
    const float peak_val = sv[0];
    __syncthreads();

    // Phase 2: last bad index < peak (max), first bad index > peak (min).
    int lb = -1, fb = NT;
#pragma unroll
    for (int k = 0; k < NT / 1024; ++k) {
        int t = tid + 1024 * k;
        float v = srow[t];
        bool bad = fabsf(v - peak_val) > delta;
        if (bad) {
            if (t < peak && t > lb) lb = t;
            if (t > peak && t < fb) fb = t;
        }
    }
    __shared__ int slb[1024];
    __shared__ int sfb[1024];
    slb[tid] = lb; sfb[tid] = fb;
    __syncthreads();
    for (int off = 512; off > 0; off >>= 1) {
        if (tid < off) {
            slb[tid] = max(slb[tid], slb[tid + off]);
            sfb[tid] = min(sfb[tid], sfb[tid + off]);
        }
        __syncthreads();
    }

    if (tid == 0) {
        const int last_bad  = slb[0];
        const int first_bad = sfb[0];
        const int start0 = last_bad + 1;
        const int start  = (start0 == peak) ? start0 : start0 + 1;
        const int end0   = first_bad - 1;
        const int end    = (end0 == peak) ? end0 : end0 - 1;
        out[b]      = start;   // output 0: start, int32
        out[NB + b] = end;     // output 1: end,   int32
    }
}

// ---------------------------------------------------------------------------
extern "C" void kernel_launch(void* const* d_in, const int* in_sizes, int n_in,
                              void* d_out, int out_size, void* d_ws, size_t ws_size,
                              hipStream_t stream) {
    const float* video   = (const float*)d_in[0];   // (64, 4096, 1024) f32
    const float* lang    = (const float*)d_in[1];   // (64, 1, 1024)    f32
    const float* delta_p = (const float*)d_in[2];   // scalar f32
    int* out = (int*)d_out;                         // 64 starts, then 64 ends

    float* sim = (float*)d_ws;                      // 262144 floats

    const int rows = NB * NT;                       // 262144 rows, 4 rows/block
    sim_kernel<<<rows / 4, 256, 0, stream>>>(video, lang, sim);

    segment_kernel<<<NB, 1024, 0, stream>>>(sim, delta_p, out);
}